// Round 3
// baseline (1045.054 us; speedup 1.0000x reference)
//
#include <hip/hip_runtime.h>

#define BATCH 64
#define TT    1024
#define INC   16
#define NN    512
#define RNK   16
#define OUTC  8

// a = DT/TAU = 0.1
#define A_COEF 0.1f

__device__ __forceinline__ float fast_tanh(float x) {
    // tanh(x) = 1 - 2/(exp(2x)+1); safe at +/-inf
    float e = __expf(2.0f * x);
    return 1.0f - __fdividef(2.0f, e + 1.0f);
}

// Barrier with LDS ordering only (does NOT drain vmcnt: global stores/loads
// in flight are never ordered by this barrier).
__device__ __forceinline__ void lgkm_barrier() {
    asm volatile("s_waitcnt lgkmcnt(0)\n\ts_barrier" ::: "memory");
}

// ---- DPP cross-lane adds (VALU pipe) ----
template<int CTRL>
__device__ __forceinline__ float dpp_add(float x) {
    int y = __builtin_amdgcn_update_dpp(0, __float_as_int(x), CTRL, 0xF, 0xF, true);
    return x + __int_as_float(y);
}

// Sum over each 32-lane half-wave; result valid in lanes 31 and 63.
__device__ __forceinline__ float half_wave_sum(float x) {
    x = dpp_add<0x111>(x);  // row_shr:1
    x = dpp_add<0x112>(x);  // row_shr:2
    x = dpp_add<0x114>(x);  // row_shr:4
    x = dpp_add<0x118>(x);  // row_shr:8
    x = dpp_add<0x142>(x);  // row_bcast15 -> 32-group sums at lanes 31/63
    return x;
}

// Full 64-lane sum; result valid in lane 63.
__device__ __forceinline__ float wave_sum(float x) {
    x = half_wave_sum(x);
    x = dpp_add<0x143>(x);  // row_bcast31
    return x;
}

// ---- packed dual-FP32 FMA (CDNA VOP3P; exact f32 fma semantics) ----
// d = a * b + c, elementwise on 2-wide packs.
__device__ __forceinline__ float2 pk_fma_blo(float2 a, float2 b, float2 c) {
    // both halves of result use b.lo : d.lo = a.lo*b.lo+c.lo ; d.hi = a.hi*b.lo+c.hi
    float2 d;
    asm("v_pk_fma_f32 %0, %1, %2, %3 op_sel_hi:[1,0,1]"
        : "=v"(d) : "v"(a), "v"(b), "v"(c));
    return d;
}
__device__ __forceinline__ float2 pk_fma_bhi(float2 a, float2 b, float2 c) {
    // both halves of result use b.hi
    float2 d;
    asm("v_pk_fma_f32 %0, %1, %2, %3 op_sel:[0,1,0] op_sel_hi:[1,1,1]"
        : "=v"(d) : "v"(a), "v"(b), "v"(c));
    return d;
}

// ---------------------------------------------------------------------------
// Pre-pass: Inp[b,t,n] = sum_i x[b,t,i] * In_w[n,i].
// One wave per (b,t) row, grid-stride; In_w cached in registers (8 rows/lane).
// Memory-bound (~128 MB write); removes 32 FMA/lane/step from the scan.
// ---------------------------------------------------------------------------
__global__ __launch_bounds__(256) void inp_kernel(
    const float* __restrict__ x,     // [B,T,INC]
    const float* __restrict__ In_w,  // [N,INC]
    float* __restrict__ Inp)         // [B,T,N]
{
    const int wv = (blockIdx.x << 2) | (threadIdx.x >> 6);
    const int p  = threadIdx.x & 63;
    const int NW = gridDim.x << 2;

    // lane p owns states n = p + 64k, k=0..7
    float4 W4[8][4];
    #pragma unroll
    for (int k = 0; k < 8; ++k) {
        const float4* wr = (const float4*)&In_w[(p + 64 * k) * INC];
        W4[k][0] = wr[0]; W4[k][1] = wr[1]; W4[k][2] = wr[2]; W4[k][3] = wr[3];
    }

    const int ROWS = BATCH * TT;
    for (int r = wv; r < ROWS; r += NW) {
        const float4* xr = (const float4*)(x + (size_t)r * INC);
        float4 x0 = xr[0], x1 = xr[1], x2 = xr[2], x3 = xr[3];
        #pragma unroll
        for (int k = 0; k < 8; ++k) {
            float a = W4[k][0].x * x0.x;
            float b = W4[k][0].y * x0.y;
            float c = W4[k][0].z * x0.z;
            float d = W4[k][0].w * x0.w;
            a = fmaf(W4[k][1].x, x1.x, a);
            b = fmaf(W4[k][1].y, x1.y, b);
            c = fmaf(W4[k][1].z, x1.z, c);
            d = fmaf(W4[k][1].w, x1.w, d);
            a = fmaf(W4[k][2].x, x2.x, a);
            b = fmaf(W4[k][2].y, x2.y, b);
            c = fmaf(W4[k][2].z, x2.z, c);
            d = fmaf(W4[k][2].w, x2.w, d);
            a = fmaf(W4[k][3].x, x3.x, a);
            b = fmaf(W4[k][3].y, x3.y, b);
            c = fmaf(W4[k][3].z, x3.z, c);
            d = fmaf(W4[k][3].w, x3.w, d);
            Inp[(size_t)r * NN + p + 64 * k] = (a + b) + (c + d);  // coalesced
        }
    }
}

// ---------------------------------------------------------------------------
// Scan: 2 batches per 256-thread block (32 blocks), both batches carried by
// the SAME 4 waves (each lane runs two independent recurrence streams).
// Rationale: at 1 wave/SIMD the wave is in-order & alone; batch B's compute
// fills batch A's LDS-latency gaps. Weights (V,U) live once in registers,
// packed as float2 pairs for v_pk_fma_f32 (halves FMA issue). Inp is
// precomputed; per step each batch needs one float2 global load (prefetched
// a full step ahead). phi/low round-trip LDS with lgkm-only barriers.
// ---------------------------------------------------------------------------
__global__ __launch_bounds__(256, 1) void scan_kernel(
    const float* __restrict__ Inp,    // [B,T,N] precomputed input projection
    const float* __restrict__ V_w,    // [R,N]
    const float* __restrict__ U_w,    // [N,R]
    const float* __restrict__ h0,     // [N]
    float* __restrict__ hidden)       // [B,T,N]
{
    const int p  = threadIdx.x;      // 0..255; owns states n0=2p, n0+1
    const int rr = p >> 5;           // reduce group 0..7 -> r = rr and rr+8
    const int g  = p & 31;
    const int g4 = g * 4;
    const int n0 = p << 1;
    const int b0 = blockIdx.x * 2;

    __shared__ __align__(16) float phi_s[2][NN];
    __shared__ __align__(16) float low_s[2][RNK];

    // V pairs: Vpk[k*4+j] = (V[rr, n'], V[rr+8, n']), n' = k*128 + g*4 + j
    float2 Vpk[16];
    #pragma unroll
    for (int k = 0; k < 4; ++k)
        #pragma unroll
        for (int j = 0; j < 4; ++j) {
            int idx = k * 128 + g4 + j;
            Vpk[k * 4 + j] = make_float2(V_w[rr * NN + idx], V_w[(rr + 8) * NN + idx]);
        }

    // U pairs: Upk[r] = (U[n0,r], U[n0+1,r])
    float2 Upk[16];
    #pragma unroll
    for (int r = 0; r < RNK; ++r)
        Upk[r] = make_float2(U_w[n0 * RNK + r], U_w[(n0 + 1) * RNK + r]);

    float2 hA = ((const float2*)h0)[p];
    float2 hB = hA;

    const float* iA = Inp + (size_t)(b0 + 0) * TT * NN;
    const float* iB = Inp + (size_t)(b0 + 1) * TT * NN;
    float* oA = hidden + (size_t)(b0 + 0) * TT * NN;
    float* oB = hidden + (size_t)(b0 + 1) * TT * NN;

    float2 inA = ((const float2*)iA)[p];   // t = 0
    float2 inB = ((const float2*)iB)[p];

#define VSTEP(acc0, acc1, q, f)                                        \
    acc0 = pk_fma_blo(Vpk[(q)*4 + 0], make_float2(f.x, f.y), acc0);    \
    acc1 = pk_fma_bhi(Vpk[(q)*4 + 1], make_float2(f.x, f.y), acc1);    \
    acc0 = pk_fma_blo(Vpk[(q)*4 + 2], make_float2(f.z, f.w), acc0);    \
    acc1 = pk_fma_bhi(Vpk[(q)*4 + 3], make_float2(f.z, f.w), acc1);

#define USTEP(rec, l4, r0)                                             \
    rec = pk_fma_blo(Upk[(r0) + 0], make_float2(l4.x, l4.y), rec);     \
    rec = pk_fma_bhi(Upk[(r0) + 1], make_float2(l4.x, l4.y), rec);     \
    rec = pk_fma_blo(Upk[(r0) + 2], make_float2(l4.z, l4.w), rec);     \
    rec = pk_fma_bhi(Upk[(r0) + 3], make_float2(l4.z, l4.w), rec);

    for (int t = 0; t < TT; ++t) {
        // ---- phase A: tanh + publish phi (both batches) ----
        float2 phiA = make_float2(fast_tanh(hA.x), fast_tanh(hA.y));
        float2 phiB = make_float2(fast_tanh(hB.x), fast_tanh(hB.y));
        ((float2*)phi_s[0])[p] = phiA;
        ((float2*)phi_s[1])[p] = phiB;

        // prefetch Inp for t+1 (global b64, consumed next iter in phase C:
        // a full step of latency window; vmcnt never drained by lgkm_barrier)
        int tn = (t + 1 < TT) ? t + 1 : t;
        float2 nxA = ((const float2*)(iA + (size_t)tn * NN))[p];
        float2 nxB = ((const float2*)(iB + (size_t)tn * NN))[p];

        lgkm_barrier();   // phi visible

        // ---- phase B: low-rank gather, both batches ----
        float4 fA0 = *(const float4*)&phi_s[0][g4];
        float4 fA1 = *(const float4*)&phi_s[0][128 + g4];
        float4 fA2 = *(const float4*)&phi_s[0][256 + g4];
        float4 fA3 = *(const float4*)&phi_s[0][384 + g4];
        float4 fB0 = *(const float4*)&phi_s[1][g4];
        float4 fB1 = *(const float4*)&phi_s[1][128 + g4];
        float4 fB2 = *(const float4*)&phi_s[1][256 + g4];
        float4 fB3 = *(const float4*)&phi_s[1][384 + g4];

        float2 z = make_float2(0.f, 0.f);
        float2 aA0 = z, aA1 = z, aB0 = z, aB1 = z;
        VSTEP(aA0, aA1, 0, fA0)
        VSTEP(aA0, aA1, 1, fA1)
        VSTEP(aA0, aA1, 2, fA2)
        VSTEP(aA0, aA1, 3, fA3)
        VSTEP(aB0, aB1, 0, fB0)
        VSTEP(aB0, aB1, 1, fB1)
        VSTEP(aB0, aB1, 2, fB2)
        VSTEP(aB0, aB1, 3, fB3)
        // acc pairs hold (contrib to r=rr, contrib to r=rr+8)
        float pAa = aA0.x + aA1.x;   // batch A, r = rr
        float pAb = aA0.y + aA1.y;   // batch A, r = rr+8
        float pBa = aB0.x + aB1.x;
        float pBb = aB0.y + aB1.y;
        pAa = half_wave_sum(pAa);    // 4 independent DPP chains, pipelined
        pAb = half_wave_sum(pAb);
        pBa = half_wave_sum(pBa);
        pBb = half_wave_sum(pBb);
        if (g == 31) {
            low_s[0][rr]     = pAa;
            low_s[0][rr + 8] = pAb;
            low_s[1][rr]     = pBa;
            low_s[1][rr + 8] = pBb;
        }

        lgkm_barrier();   // low visible

        // ---- phase C: rec = U . low (+inp), h update, store ----
        float4 lA0 = *(const float4*)&low_s[0][0];
        float4 lA1 = *(const float4*)&low_s[0][4];
        float4 lA2 = *(const float4*)&low_s[0][8];
        float4 lA3 = *(const float4*)&low_s[0][12];
        float4 lB0 = *(const float4*)&low_s[1][0];
        float4 lB1 = *(const float4*)&low_s[1][4];
        float4 lB2 = *(const float4*)&low_s[1][8];
        float4 lB3 = *(const float4*)&low_s[1][12];

        float2 rA = inA;             // init accumulator with input projection
        float2 rB = inB;
        USTEP(rA, lA0, 0)
        USTEP(rA, lA1, 4)
        USTEP(rA, lA2, 8)
        USTEP(rA, lA3, 12)
        USTEP(rB, lB0, 0)
        USTEP(rB, lB1, 4)
        USTEP(rB, lB2, 8)
        USTEP(rB, lB3, 12)

        hA.x = fmaf(A_COEF, rA.x - hA.x, hA.x);   // (1-a)h + a(rec+inp)
        hA.y = fmaf(A_COEF, rA.y - hA.y, hA.y);
        hB.x = fmaf(A_COEF, rB.x - hB.x, hB.x);
        hB.y = fmaf(A_COEF, rB.y - hB.y, hB.y);

        ((float2*)(oA + (size_t)t * NN))[p] = hA;  // coalesced, fire-and-forget
        ((float2*)(oB + (size_t)t * NN))[p] = hB;

        inA = nxA;
        inB = nxB;
    }
#undef VSTEP
#undef USTEP
}

// ---------------------------------------------------------------------------
// Out-projection post-pass: out[b,t,o] = sum_n Out_w[o,n] * tanh(hidden[b,t,n])
// One wave per (b,t) row, grid-stride; memory-bound, all 256 CUs.
// ---------------------------------------------------------------------------
__global__ __launch_bounds__(256) void out_kernel(
    const float* __restrict__ hidden,  // [B,T,N]
    const float* __restrict__ Out_w,   // [OUTC,N]
    float* __restrict__ out)           // [B,T,OUTC]
{
    const int wv = (blockIdx.x << 2) | (threadIdx.x >> 6);
    const int p  = threadIdx.x & 63;
    const int NW = gridDim.x << 2;

    float Ow[OUTC][8];
    #pragma unroll
    for (int o = 0; o < OUTC; ++o) {
        float4 w0 = *(const float4*)&Out_w[o * NN + p * 4];
        float4 w1 = *(const float4*)&Out_w[o * NN + 256 + p * 4];
        Ow[o][0] = w0.x; Ow[o][1] = w0.y; Ow[o][2] = w0.z; Ow[o][3] = w0.w;
        Ow[o][4] = w1.x; Ow[o][5] = w1.y; Ow[o][6] = w1.z; Ow[o][7] = w1.w;
    }

    const int ROWS = BATCH * TT;
    for (int r = wv; r < ROWS; r += NW) {
        const float4* hp = (const float4*)(hidden + (size_t)r * NN);
        float4 a = hp[p];
        float4 c = hp[64 + p];
        float ph[8];
        ph[0] = fast_tanh(a.x); ph[1] = fast_tanh(a.y);
        ph[2] = fast_tanh(a.z); ph[3] = fast_tanh(a.w);
        ph[4] = fast_tanh(c.x); ph[5] = fast_tanh(c.y);
        ph[6] = fast_tanh(c.z); ph[7] = fast_tanh(c.w);
        #pragma unroll
        for (int o = 0; o < OUTC; ++o) {
            float sa = Ow[o][0] * ph[0];
            float sb = Ow[o][1] * ph[1];
            sa = fmaf(Ow[o][2], ph[2], sa);
            sb = fmaf(Ow[o][3], ph[3], sb);
            sa = fmaf(Ow[o][4], ph[4], sa);
            sb = fmaf(Ow[o][5], ph[5], sb);
            sa = fmaf(Ow[o][6], ph[6], sa);
            sb = fmaf(Ow[o][7], ph[7], sb);
            float s = sa + sb;
            s = wave_sum(s);
            if (p == 63) out[(size_t)r * OUTC + o] = s;
        }
    }
}

extern "C" void kernel_launch(void* const* d_in, const int* in_sizes, int n_in,
                              void* d_out, int out_size, void* d_ws, size_t ws_size,
                              hipStream_t stream) {
    const float* x    = (const float*)d_in[0];  // [64,1024,16]
    const float* In_w = (const float*)d_in[1];  // [512,16]
    const float* V_w  = (const float*)d_in[2];  // [16,512]
    const float* U_w  = (const float*)d_in[3];  // [512,16]
    const float* Ow   = (const float*)d_in[4];  // [8,512]
    const float* h0   = (const float*)d_in[5];  // [512]

    float* hidden = (float*)d_out;                         // [64,1024,512]
    float* out    = hidden + (size_t)BATCH * TT * NN;      // [64,1024,8]
    float* Inp    = (float*)d_ws;                          // [64,1024,512] workspace

    // 1) input projection (memory-bound, ~30 us)
    inp_kernel<<<1024, 256, 0, stream>>>(x, In_w, Inp);
    // 2) recurrent scan: 32 blocks x 256 thr, 2 batches per block
    scan_kernel<<<BATCH / 2, 256, 0, stream>>>(Inp, V_w, U_w, h0, hidden);
    // 3) out-projection from stored hidden (memory-bound, ~40 us)
    out_kernel<<<1024, 256, 0, stream>>>(hidden, Ow, out);
}